// Round 5
// baseline (412.444 us; speedup 1.0000x reference)
//
#include <hip/hip_runtime.h>

#define B_ 256
#define S_ 1024
#define D_ 128
#define H_ 256

typedef short short8 __attribute__((ext_vector_type(8)));
typedef float f32x4 __attribute__((ext_vector_type(4)));

// Cross-kernel buffers (re-written every call).
__device__ unsigned short g_Wb0[H_ * D_];   // bf16 left-halves, FRAG-ORDERED
__device__ unsigned short g_Wb1[H_ * H_];
__device__ unsigned short g_Wb2[H_ * H_];
__device__ float g_Wc0[H_ * D_];            // fp32: W_right + (W_left - bf16(W_left))
__device__ float g_Wc1[H_ * H_];
__device__ float g_Wc2[H_ * H_];
__device__ float g_colsum1[B_ * H_];        // column sums of layer outputs (atomic)
__device__ float g_colsum2[B_ * H_];
__device__ float g_c0[B_ * H_];             // per-set bias+mean vectors
__device__ float g_c1[B_ * H_];
__device__ float g_c2[B_ * H_];
__device__ unsigned short g_xb[(size_t)B_ * S_ * D_];  // bf16 x, row-swizzled (64 MiB)

__device__ __forceinline__ unsigned short f2bf(float x) {
    union { float f; unsigned u; } v; v.f = x;
    unsigned r = v.u + 0x7FFFu + ((v.u >> 16) & 1u);
    return (unsigned short)(r >> 16);
}
__device__ __forceinline__ float bf2f(unsigned short h) {
    union { float f; unsigned u; } v; v.u = ((unsigned)h) << 16;
    return v.f;
}
__device__ __forceinline__ float fast_tanh(float x) {
    float e = __builtin_amdgcn_exp2f(x * 2.885390081777927f); // 2*log2(e)
    float r = __builtin_amdgcn_rcpf(1.0f + e);
    return 1.0f - 2.0f * r;
}
__device__ __forceinline__ unsigned cvt_pk_bf16(float lo, float hi) {
    unsigned r;
    asm("v_cvt_pk_bf16_f32 %0, %1, %2" : "=v"(r) : "v"(lo), "v"(hi));
    return r;
}
__device__ __forceinline__ void gload_lds16(const unsigned short* g, unsigned short* l) {
    __builtin_amdgcn_global_load_lds(
        (const __attribute__((address_space(1))) void*)g,
        (__attribute__((address_space(3))) void*)l, 16, 0, 0);
}
// Sum across each 16-lane group (DPP row_shr chain, pure VALU).
// Lane (l&15)==15 of each group ends up holding the 16-lane total.
__device__ __forceinline__ float row16_reduce_add(float v) {
    int s;
    s = __builtin_amdgcn_update_dpp(0, __builtin_bit_cast(int, v), 0x111, 0xF, 0xF, true);
    v += __builtin_bit_cast(float, s);
    s = __builtin_amdgcn_update_dpp(0, __builtin_bit_cast(int, v), 0x112, 0xF, 0xF, true);
    v += __builtin_bit_cast(float, s);
    s = __builtin_amdgcn_update_dpp(0, __builtin_bit_cast(int, v), 0x114, 0xF, 0xF, true);
    v += __builtin_bit_cast(float, s);
    s = __builtin_amdgcn_update_dpp(0, __builtin_bit_cast(int, v), 0x118, 0xF, 0xF, true);
    v += __builtin_bit_cast(float, s);
    return v;
}

// ---- prep: W -> bf16 frag-ordered + fp32 correction; zero colsums and out --
__global__ __launch_bounds__(256) void prep_kernel(
    const float* __restrict__ W0, const float* __restrict__ W1,
    const float* __restrict__ W2, float* __restrict__ out)
{
    int i = blockIdx.x * 256 + threadIdx.x;
    const float* W; unsigned short* wb; float* wc; int kbits;
    if (i < H_ * D_) { W = W0; wb = g_Wb0; wc = g_Wc0; kbits = 7; }
    else {
        i -= H_ * D_;
        if (i < H_ * H_) { W = W1; wb = g_Wb1; wc = g_Wc1; kbits = 8; }
        else {
            i -= H_ * H_;
            if (i < H_ * H_) { W = W2; wb = g_Wb2; wc = g_Wc2; kbits = 8; }
            else {
                i -= H_ * H_;
                if (i < B_ * H_) { g_colsum1[i] = 0.f; return; }
                i -= B_ * H_;
                if (i < B_ * H_) { g_colsum2[i] = 0.f; return; }
                i -= B_ * H_;
                if (i < B_ * H_) { out[i] = 0.f; }
                return;
            }
        }
    }
    const int K = 1 << kbits, KS = K >> 5;
    const int n = i >> kbits, k = i & (K - 1);
    const float a = W[n * 2 * K + k];
    const float b = W[n * 2 * K + K + k];
    const unsigned short hb = f2bf(a);
    // frag order: [w][cf][ks][lane][e] with lane = quad*16 + l15
    const int w = n >> 5, cf = (n >> 4) & 1, l15 = n & 15;
    const int ks = k >> 5, quad = (k >> 3) & 3, e = k & 7;
    wb[(((w * 2 + cf) * KS + ks) * 64 + quad * 16 + l15) * 8 + e] = hb;
    wc[n * K + k] = b + (a - bf2f(hb));
}

// ---- means0: col sums of x + bf16 swizzled copy + FUSED c0 computation -----
__global__ __launch_bounds__(1024) void means0_kernel(
    const float* __restrict__ x, const float* __restrict__ b0)
{
    const int set = blockIdx.x, t = threadIdx.x;
    const int cg = t & 31, rg = t >> 5;               // col-group of 4, row group
    const float* xs = x + (size_t)set * S_ * D_;
    unsigned short* xd = g_xb + (size_t)set * S_ * D_;
    const int slot = cg >> 1, halfsel = (cg & 1) * 4;
    f32x4 s = (f32x4){0.f, 0.f, 0.f, 0.f};
    #pragma unroll 8
    for (int i = 0; i < 32; ++i) {
        const int row = rg + i * 32;
        f32x4 v = *(const f32x4*)(xs + row * D_ + cg * 4);
        s += v;
        uint2 pv;
        pv.x = cvt_pk_bf16(v[0], v[1]);
        pv.y = cvt_pk_bf16(v[2], v[3]);
        *(uint2*)(&xd[row * D_ + ((slot ^ (row & 7)) * 8) + halfsel]) = pv;
    }
    __shared__ f32x4 red[32][32];
    __shared__ float m_lds[D_];
    red[rg][cg] = s;
    __syncthreads();
    if (t < 32) {
        f32x4 a = red[0][t];
        #pragma unroll
        for (int g = 1; g < 32; ++g) a += red[g][t];
        #pragma unroll
        for (int c = 0; c < 4; ++c) m_lds[t * 4 + c] = a[c] * (1.f / S_);
    }
    __syncthreads();
    // c0[set][j] = b0[j] + mean . Wc0[j]   (Wc0 is L2-resident, 128 KB)
    if (t < H_) {
        const float* wr = g_Wc0 + t * D_;
        float acc = 0.f;
        #pragma unroll 4
        for (int k = 0; k < D_; k += 4) {
            f32x4 w = *(const f32x4*)(wr + k);
            #pragma unroll
            for (int c = 0; c < 4; ++c) acc += m_lds[k + c] * w[c];
        }
        g_c0[set * H_ + t] = b0[t] + acc;
    }
}

// ---- c-vector kernel (layers 1,2): c[set][j] = bias[j] + mean[set].Wc[j] ---
// grid 64: block handles 4 sets x all 256 cols; Wc read once per block.
template <int L>
__global__ __launch_bounds__(256) void c_kernel(const float* __restrict__ bias)
{
    const int j = threadIdx.x, sg = blockIdx.x * 4;
    const float* Wc = (L == 1) ? g_Wc1 : g_Wc2;
    const float* ms = (L == 1) ? g_colsum1 : g_colsum2;
    float* dst = (L == 1) ? g_c1 : g_c2;
    __shared__ float m_lds[4][H_];
    for (int i = j; i < 4 * H_; i += 256)
        m_lds[i >> 8][i & (H_ - 1)] = ms[(sg + (i >> 8)) * H_ + (i & (H_ - 1))] * (1.f / S_);
    __syncthreads();
    const float* wr = Wc + j * H_;
    float a0 = 0.f, a1 = 0.f, a2 = 0.f, a3 = 0.f;
    #pragma unroll 4
    for (int k = 0; k < H_; k += 4) {
        f32x4 w = *(const f32x4*)(wr + k);
        #pragma unroll
        for (int c = 0; c < 4; ++c) {
            a0 += m_lds[0][k + c] * w[c];
            a1 += m_lds[1][k + c] * w[c];
            a2 += m_lds[2][k + c] * w[c];
            a3 += m_lds[3][k + c] * w[c];
        }
    }
    const float bb = bias[j];
    dst[(sg + 0) * H_ + j] = bb + a0;
    dst[(sg + 1) * H_ + j] = bb + a1;
    dst[(sg + 2) * H_ + j] = bb + a2;
    dst[(sg + 3) * H_ + j] = bb + a3;
}

// ---- layer: grid=512 (2 blocks per set = 2 blocks/CU), 512 thr / 8 waves --
// W-fragments in registers (wave owns 32 output cols); y/x streamed in
// 64-row tiles through LDS via async global_load_lds, double-buffered
// (issue stage(t+1), compute t, one barrier per tile). With 2 resident
// blocks/CU, one block's barrier drain overlaps the other's compute.
// Global y/xb are row-swizzled (slot ^= row&7) so the linear LDS copy yields
// bank-spread ds_read_b128. Colsums: register accumulation -> DPP reduce ->
// global atomicAdd (prep-zeroed) to combine the two half-set blocks.
template <int LAYER>
__global__ __launch_bounds__(512, 4) void layer_kernel(
    unsigned short* ybuf, float* __restrict__ out)
{
    constexpr int K  = (LAYER == 0) ? D_ : H_;
    constexpr int KS = K / 32;
    constexpr int NCH = (64 * K / 8) / 512;   // 16B chunks per thread per tile
    constexpr int NT = 8;                     // 8 tiles of 64 rows = half a set
    const int set = blockIdx.x >> 1;
    const int rh  = blockIdx.x & 1;
    const int t = threadIdx.x;
    const int lane = t & 63, wave = t >> 6;
    const int l15 = lane & 15, quad = lane >> 4;

    __shared__ __align__(16) unsigned short y_lds[2][64 * K];

    const unsigned short* Wb = (LAYER == 0) ? g_Wb0 : (LAYER == 1) ? g_Wb1 : g_Wb2;
    const float* cvec = (LAYER == 0) ? g_c0 : (LAYER == 1) ? g_c1 : g_c2;
    const unsigned short* ysrc = (LAYER == 0)
        ? g_xb + ((size_t)set * S_ + rh * 512) * D_
        : ybuf + ((size_t)set * S_ + rh * 512) * H_;
    unsigned short* ydst = ybuf + ((size_t)set * S_ + rh * 512) * H_;

    // W fragments: frag-ordered global layout -> perfectly coalesced b128 loads
    short8 wf[2][KS];
    {
        const unsigned short* wb = Wb + (wave * 2 * KS * 64 + lane) * 8;
        #pragma unroll
        for (int cf = 0; cf < 2; ++cf)
            #pragma unroll
            for (int ks = 0; ks < KS; ++ks)
                wf[cf][ks] = *(const short8*)(wb + (cf * KS + ks) * 512);
    }
    const float* cv = cvec + set * H_ + wave * 32 + quad * 4;
    f32x4 creg0 = *(const f32x4*)(cv);
    f32x4 creg1 = *(const f32x4*)(cv + 16);

    // stage tile 0
    #pragma unroll
    for (int c = 0; c < NCH; ++c)
        gload_lds16(ysrc + (c * 512 + t) * 8, &y_lds[0][(c * 512 + t) * 8]);

    f32x4 cs0 = (f32x4){0.f, 0.f, 0.f, 0.f};
    f32x4 cs1 = (f32x4){0.f, 0.f, 0.f, 0.f};
    __syncthreads();

    for (int tt = 0; tt < NT; ++tt) {
        const int buf = tt & 1;
        if (tt + 1 < NT) {
            const unsigned short* src = ysrc + (tt + 1) * 64 * K;
            #pragma unroll
            for (int c = 0; c < NCH; ++c)
                gload_lds16(src + (c * 512 + t) * 8, &y_lds[buf ^ 1][(c * 512 + t) * 8]);
        }
        const unsigned short* yl = y_lds[buf];
        #pragma unroll
        for (int rf = 0; rf < 4; ++rf) {
            short8 bfr[KS];
            #pragma unroll
            for (int ks = 0; ks < KS; ++ks)
                bfr[ks] = *(const short8*)(
                    &yl[(rf * 16 + l15) * K + (((ks * 4 + quad) ^ (l15 & 7)) * 8)]);
            f32x4 ac0 = (f32x4){0.f, 0.f, 0.f, 0.f};
            f32x4 ac1 = (f32x4){0.f, 0.f, 0.f, 0.f};
            #pragma unroll
            for (int ks = 0; ks < KS; ++ks) {
                ac0 = __builtin_amdgcn_mfma_f32_16x16x32_bf16(wf[0][ks], bfr[ks], ac0, 0, 0, 0);
                ac1 = __builtin_amdgcn_mfma_f32_16x16x32_bf16(wf[1][ks], bfr[ks], ac1, 0, 0, 0);
            }
            // D layout: lane -> local row = tt*64+rf*16+l15 (B op),
            // cols = wave*32 + cf*16 + quad*4 + r (A op)
            const int lr = tt * 64 + rf * 16 + l15;   // lr&7 == l15&7 == row&7
            f32x4 th0, th1;
            #pragma unroll
            for (int r = 0; r < 4; ++r) th0[r] = fast_tanh(ac0[r] + creg0[r]);
            #pragma unroll
            for (int r = 0; r < 4; ++r) th1[r] = fast_tanh(ac1[r] + creg1[r]);
            cs0 += th0; cs1 += th1;
            if (LAYER < 2) {
                const int slot0 = wave * 4 + (quad >> 1);     // cf=0
                const int slot1 = slot0 + 2;                  // cf=1
                uint2 p0, p1;
                p0.x = cvt_pk_bf16(th0[0], th0[1]); p0.y = cvt_pk_bf16(th0[2], th0[3]);
                p1.x = cvt_pk_bf16(th1[0], th1[1]); p1.y = cvt_pk_bf16(th1[2], th1[3]);
                unsigned short* yr = ydst + lr * H_ + (quad & 1) * 4;
                *(uint2*)(&yr[(slot0 ^ (lr & 7)) * 8]) = p0;
                *(uint2*)(&yr[(slot1 ^ (lr & 7)) * 8]) = p1;
            }
        }
        __syncthreads();   // drains vmcnt (stage + y-stores); buf swap safe
    }

    // colsum finalize: 16-lane DPP reduce; lane l15==15 atomically adds its
    // 4 cols per cf into the prep-zeroed global accumulator (2 blocks/set).
    #pragma unroll
    for (int r = 0; r < 4; ++r) {
        cs0[r] = row16_reduce_add(cs0[r]);
        cs1[r] = row16_reduce_add(cs1[r]);
    }
    if (l15 == 15) {
        const int col = wave * 32 + quad * 4;
        if (LAYER == 2) {
            #pragma unroll
            for (int r = 0; r < 4; ++r) {
                atomicAdd(&out[set * H_ + col + r],      cs0[r] * (1.f / S_));
                atomicAdd(&out[set * H_ + col + 16 + r], cs1[r] * (1.f / S_));
            }
        } else if (LAYER == 1) {
            #pragma unroll
            for (int r = 0; r < 4; ++r) {
                atomicAdd(&g_colsum2[set * H_ + col + r],      cs0[r]);
                atomicAdd(&g_colsum2[set * H_ + col + 16 + r], cs1[r]);
            }
        } else {
            #pragma unroll
            for (int r = 0; r < 4; ++r) {
                atomicAdd(&g_colsum1[set * H_ + col + r],      cs0[r]);
                atomicAdd(&g_colsum1[set * H_ + col + 16 + r], cs1[r]);
            }
        }
    }
}

extern "C" void kernel_launch(void* const* d_in, const int* in_sizes, int n_in,
                              void* d_out, int out_size, void* d_ws, size_t ws_size,
                              hipStream_t stream) {
    (void)in_sizes; (void)n_in; (void)out_size; (void)ws_size;
    const float* x  = (const float*)d_in[0];
    const float* W0 = (const float*)d_in[1];
    const float* b0 = (const float*)d_in[2];
    const float* W1 = (const float*)d_in[3];
    const float* b1 = (const float*)d_in[4];
    const float* W2 = (const float*)d_in[5];
    const float* b2 = (const float*)d_in[6];
    float* out = (float*)d_out;
    unsigned short* ws = (unsigned short*)d_ws;   // y: [256][1024][256] bf16 = 128 MiB

    prep_kernel<<<dim3(1408), dim3(256), 0, stream>>>(W0, W1, W2, out);
    means0_kernel<<<dim3(256), dim3(1024), 0, stream>>>(x, b0);
    layer_kernel<0><<<dim3(512), dim3(512), 0, stream>>>(ws, out);
    c_kernel<1><<<dim3(64), dim3(256), 0, stream>>>(b1);
    layer_kernel<1><<<dim3(512), dim3(512), 0, stream>>>(ws, out);
    c_kernel<2><<<dim3(64), dim3(256), 0, stream>>>(b2);
    layer_kernel<2><<<dim3(512), dim3(512), 0, stream>>>(ws, out);
}

// Round 6
// 380.574 us; speedup vs baseline: 1.0837x; 1.0837x over previous
//
#include <hip/hip_runtime.h>

#define B_ 256
#define S_ 1024
#define D_ 128
#define H_ 256

typedef short short8 __attribute__((ext_vector_type(8)));
typedef float f32x4 __attribute__((ext_vector_type(4)));

// Cross-kernel buffers (re-written every call).
__device__ unsigned short g_Wb0[H_ * D_];   // bf16 left-halves, FRAG-ORDERED
__device__ unsigned short g_Wb1[H_ * H_];
__device__ unsigned short g_Wb2[H_ * H_];
__device__ float g_Wc0[H_ * D_];            // fp32: W_right + (W_left - bf16(W_left))
__device__ float g_Wc1[H_ * H_];
__device__ float g_Wc2[H_ * H_];
__device__ float g_colsum1[B_ * H_];        // column sums of layer outputs
__device__ float g_colsum2[B_ * H_];
__device__ float g_c0[B_ * H_];             // per-set bias+mean vectors
__device__ float g_c1[B_ * H_];
__device__ float g_c2[B_ * H_];
__device__ unsigned short g_xb[(size_t)B_ * S_ * D_];  // bf16 x, row-swizzled (64 MiB)

__device__ __forceinline__ unsigned short f2bf(float x) {
    union { float f; unsigned u; } v; v.f = x;
    unsigned r = v.u + 0x7FFFu + ((v.u >> 16) & 1u);
    return (unsigned short)(r >> 16);
}
__device__ __forceinline__ float bf2f(unsigned short h) {
    union { float f; unsigned u; } v; v.u = ((unsigned)h) << 16;
    return v.f;
}
__device__ __forceinline__ float fast_tanh(float x) {
    float e = __builtin_amdgcn_exp2f(x * 2.885390081777927f); // 2*log2(e)
    float r = __builtin_amdgcn_rcpf(1.0f + e);
    return 1.0f - 2.0f * r;
}
__device__ __forceinline__ unsigned cvt_pk_bf16(float lo, float hi) {
    unsigned r;
    asm("v_cvt_pk_bf16_f32 %0, %1, %2" : "=v"(r) : "v"(lo), "v"(hi));
    return r;
}
__device__ __forceinline__ void gload_lds16(const unsigned short* g, unsigned short* l) {
    __builtin_amdgcn_global_load_lds(
        (const __attribute__((address_space(1))) void*)g,
        (__attribute__((address_space(3))) void*)l, 16, 0, 0);
}
// Sum across each 16-lane group (DPP row_shr chain, pure VALU).
// Lane (l&15)==15 of each group ends up holding the 16-lane total.
__device__ __forceinline__ float row16_reduce_add(float v) {
    int s;
    s = __builtin_amdgcn_update_dpp(0, __builtin_bit_cast(int, v), 0x111, 0xF, 0xF, true);
    v += __builtin_bit_cast(float, s);
    s = __builtin_amdgcn_update_dpp(0, __builtin_bit_cast(int, v), 0x112, 0xF, 0xF, true);
    v += __builtin_bit_cast(float, s);
    s = __builtin_amdgcn_update_dpp(0, __builtin_bit_cast(int, v), 0x114, 0xF, 0xF, true);
    v += __builtin_bit_cast(float, s);
    s = __builtin_amdgcn_update_dpp(0, __builtin_bit_cast(int, v), 0x118, 0xF, 0xF, true);
    v += __builtin_bit_cast(float, s);
    return v;
}

// ---- prep: W left-halves -> bf16 frag-ordered; Wc fp32 correction ----------
__global__ __launch_bounds__(256) void prep_kernel(
    const float* __restrict__ W0, const float* __restrict__ W1,
    const float* __restrict__ W2)
{
    int i = blockIdx.x * 256 + threadIdx.x;
    const float* W; unsigned short* wb; float* wc; int kbits;
    if (i < H_ * D_) { W = W0; wb = g_Wb0; wc = g_Wc0; kbits = 7; }
    else {
        i -= H_ * D_;
        if (i < H_ * H_) { W = W1; wb = g_Wb1; wc = g_Wc1; kbits = 8; }
        else {
            i -= H_ * H_;
            if (i >= H_ * H_) return;
            W = W2; wb = g_Wb2; wc = g_Wc2; kbits = 8;
        }
    }
    const int K = 1 << kbits, KS = K >> 5;
    const int n = i >> kbits, k = i & (K - 1);
    const float a = W[n * 2 * K + k];
    const float b = W[n * 2 * K + K + k];
    const unsigned short hb = f2bf(a);
    // frag order: [w][cf][ks][lane][e] with lane = quad*16 + l15
    const int w = n >> 5, cf = (n >> 4) & 1, l15 = n & 15;
    const int ks = k >> 5, quad = (k >> 3) & 3, e = k & 7;
    wb[(((w * 2 + cf) * KS + ks) * 64 + quad * 16 + l15) * 8 + e] = hb;
    wc[n * K + k] = b + (a - bf2f(hb));
}

// ---- means0: col sums of x + bf16 swizzled copy + FUSED c0 computation -----
__global__ __launch_bounds__(1024) void means0_kernel(
    const float* __restrict__ x, const float* __restrict__ b0)
{
    const int set = blockIdx.x, t = threadIdx.x;
    const int cg = t & 31, rg = t >> 5;               // col-group of 4, row group
    const float* xs = x + (size_t)set * S_ * D_;
    unsigned short* xd = g_xb + (size_t)set * S_ * D_;
    const int slot = cg >> 1, halfsel = (cg & 1) * 4;
    f32x4 s = (f32x4){0.f, 0.f, 0.f, 0.f};
    #pragma unroll 8
    for (int i = 0; i < 32; ++i) {
        const int row = rg + i * 32;
        f32x4 v = *(const f32x4*)(xs + row * D_ + cg * 4);
        s += v;
        uint2 pv;
        pv.x = cvt_pk_bf16(v[0], v[1]);
        pv.y = cvt_pk_bf16(v[2], v[3]);
        *(uint2*)(&xd[row * D_ + ((slot ^ (row & 7)) * 8) + halfsel]) = pv;
    }
    __shared__ f32x4 red[32][32];
    __shared__ float m_lds[D_];
    red[rg][cg] = s;
    __syncthreads();
    if (t < 32) {
        f32x4 a = red[0][t];
        #pragma unroll
        for (int g = 1; g < 32; ++g) a += red[g][t];
        #pragma unroll
        for (int c = 0; c < 4; ++c) m_lds[t * 4 + c] = a[c] * (1.f / S_);
    }
    __syncthreads();
    // c0[set][j] = b0[j] + mean . Wc0[j]   (Wc0 is L2-resident, 128 KB)
    if (t < H_) {
        const float* wr = g_Wc0 + t * D_;
        float acc = 0.f;
        #pragma unroll 4
        for (int k = 0; k < D_; k += 4) {
            f32x4 w = *(const f32x4*)(wr + k);
            #pragma unroll
            for (int c = 0; c < 4; ++c) acc += m_lds[k + c] * w[c];
        }
        g_c0[set * H_ + t] = b0[t] + acc;
    }
}

// ---- c-vector kernel (layers 1,2): c[set][j] = bias[j] + mean[set].Wc[j] ---
// grid 64: block handles 4 sets x all 256 cols; Wc read once per block.
template <int L>
__global__ __launch_bounds__(256) void c_kernel(const float* __restrict__ bias)
{
    const int j = threadIdx.x, sg = blockIdx.x * 4;
    const float* Wc = (L == 1) ? g_Wc1 : g_Wc2;
    const float* ms = (L == 1) ? g_colsum1 : g_colsum2;
    float* dst = (L == 1) ? g_c1 : g_c2;
    __shared__ float m_lds[4][H_];
    for (int i = j; i < 4 * H_; i += 256)
        m_lds[i >> 8][i & (H_ - 1)] = ms[(sg + (i >> 8)) * H_ + (i & (H_ - 1))] * (1.f / S_);
    __syncthreads();
    const float* wr = Wc + j * H_;
    float a0 = 0.f, a1 = 0.f, a2 = 0.f, a3 = 0.f;
    #pragma unroll 4
    for (int k = 0; k < H_; k += 4) {
        f32x4 w = *(const f32x4*)(wr + k);
        #pragma unroll
        for (int c = 0; c < 4; ++c) {
            a0 += m_lds[0][k + c] * w[c];
            a1 += m_lds[1][k + c] * w[c];
            a2 += m_lds[2][k + c] * w[c];
            a3 += m_lds[3][k + c] * w[c];
        }
    }
    const float bb = bias[j];
    dst[(sg + 0) * H_ + j] = bb + a0;
    dst[(sg + 1) * H_ + j] = bb + a1;
    dst[(sg + 2) * H_ + j] = bb + a2;
    dst[(sg + 3) * H_ + j] = bb + a3;
}

// ---- layer: grid=256 (one block per set), 512 thr / 8 waves ---------------
// W-fragments in registers (wave owns 32 output cols); y/x streamed in
// 64-row tiles through LDS via async global_load_lds, double-buffered.
// KEY (r6): counted-wait sync instead of __syncthreads. Per tile:
//   { s_waitcnt vmcnt(0); s_barrier; issue loads(t+1); compute t }
// The tile-(t+1) loads are issued AFTER the barrier and not waited on until
// the NEXT iteration's wait -> a full tile period in flight (vs r4's
// __syncthreads at loop end, which drained the just-issued prefetch).
// vmcnt(0) at the wait point only covers tile-t loads (needed) plus ~settled
// stores -> no fragile store-count assumptions. Buffer overwrite is safe:
// loads(t+1) target the buffer last read in compute(t-1), and every wave
// passed barrier(t) only after finishing compute(t-1).
// Colsums: register accumulation (wave owns its cols for the whole set) ->
// DPP reduce -> one direct global store. No atomics, no zero-init.
template <int LAYER>
__global__ __launch_bounds__(512, 2) void layer_kernel(
    unsigned short* ybuf, float* __restrict__ out)
{
    constexpr int K  = (LAYER == 0) ? D_ : H_;
    constexpr int KS = K / 32;
    constexpr int NCH = (64 * K / 8) / 512;   // 16B chunks per thread per tile
    constexpr int NT = S_ / 64;               // 16 tiles
    const int set = blockIdx.x;
    const int t = threadIdx.x;
    const int lane = t & 63, wave = t >> 6;
    const int l15 = lane & 15, quad = lane >> 4;

    __shared__ __align__(16) unsigned short y_lds[2][64 * K];

    const unsigned short* Wb = (LAYER == 0) ? g_Wb0 : (LAYER == 1) ? g_Wb1 : g_Wb2;
    const float* cvec = (LAYER == 0) ? g_c0 : (LAYER == 1) ? g_c1 : g_c2;
    const unsigned short* ysrc = (LAYER == 0) ? g_xb + (size_t)set * S_ * D_
                                              : ybuf + (size_t)set * S_ * H_;
    unsigned short* ydst = ybuf + (size_t)set * S_ * H_;

    // W fragments: frag-ordered global layout -> perfectly coalesced b128 loads
    short8 wf[2][KS];
    {
        const unsigned short* wb = Wb + (wave * 2 * KS * 64 + lane) * 8;
        #pragma unroll
        for (int cf = 0; cf < 2; ++cf)
            #pragma unroll
            for (int ks = 0; ks < KS; ++ks)
                wf[cf][ks] = *(const short8*)(wb + (cf * KS + ks) * 512);
    }
    const float* cv = cvec + set * H_ + wave * 32 + quad * 4;
    f32x4 creg0 = *(const f32x4*)(cv);
    f32x4 creg1 = *(const f32x4*)(cv + 16);

    // stage tile 0
    #pragma unroll
    for (int c = 0; c < NCH; ++c)
        gload_lds16(ysrc + (c * 512 + t) * 8, &y_lds[0][(c * 512 + t) * 8]);

    f32x4 cs0 = (f32x4){0.f, 0.f, 0.f, 0.f};
    f32x4 cs1 = (f32x4){0.f, 0.f, 0.f, 0.f};

    for (int tt = 0; tt < NT; ++tt) {
        const int buf = tt & 1;
        // wait: this wave's tile-tt loads retired; barrier: everyone's are.
        asm volatile("s_waitcnt vmcnt(0)" ::: "memory");
        __builtin_amdgcn_s_barrier();
        __builtin_amdgcn_sched_barrier(0);
        if (tt + 1 < NT) {
            const unsigned short* src = ysrc + (tt + 1) * 64 * K;
            #pragma unroll
            for (int c = 0; c < NCH; ++c)
                gload_lds16(src + (c * 512 + t) * 8, &y_lds[buf ^ 1][(c * 512 + t) * 8]);
        }
        const unsigned short* yl = y_lds[buf];
        #pragma unroll
        for (int rf = 0; rf < 4; ++rf) {
            short8 bfr[KS];
            #pragma unroll
            for (int ks = 0; ks < KS; ++ks)
                bfr[ks] = *(const short8*)(
                    &yl[(rf * 16 + l15) * K + (((ks * 4 + quad) ^ (l15 & 7)) * 8)]);
            f32x4 ac0 = (f32x4){0.f, 0.f, 0.f, 0.f};
            f32x4 ac1 = (f32x4){0.f, 0.f, 0.f, 0.f};
            #pragma unroll
            for (int ks = 0; ks < KS; ++ks) {
                ac0 = __builtin_amdgcn_mfma_f32_16x16x32_bf16(wf[0][ks], bfr[ks], ac0, 0, 0, 0);
                ac1 = __builtin_amdgcn_mfma_f32_16x16x32_bf16(wf[1][ks], bfr[ks], ac1, 0, 0, 0);
            }
            // D layout: lane -> y-row = tt*64+rf*16+l15 (B op),
            // cols = wave*32 + cf*16 + quad*4 + r (A op)
            const int row = tt * 64 + rf * 16 + l15;   // row&7 == l15&7
            f32x4 th0, th1;
            #pragma unroll
            for (int r = 0; r < 4; ++r) th0[r] = fast_tanh(ac0[r] + creg0[r]);
            #pragma unroll
            for (int r = 0; r < 4; ++r) th1[r] = fast_tanh(ac1[r] + creg1[r]);
            cs0 += th0; cs1 += th1;
            if (LAYER < 2) {
                const int slot0 = wave * 4 + (quad >> 1);     // cf=0
                const int slot1 = slot0 + 2;                  // cf=1
                uint2 p0, p1;
                p0.x = cvt_pk_bf16(th0[0], th0[1]); p0.y = cvt_pk_bf16(th0[2], th0[3]);
                p1.x = cvt_pk_bf16(th1[0], th1[1]); p1.y = cvt_pk_bf16(th1[2], th1[3]);
                unsigned short* yr = ydst + row * H_ + (quad & 1) * 4;
                *(uint2*)(&yr[(slot0 ^ (row & 7)) * 8]) = p0;
                *(uint2*)(&yr[(slot1 ^ (row & 7)) * 8]) = p1;
            }
        }
    }

    // colsum finalize: 16-lane DPP reduce; lane l15==15 stores its 4 cols per cf
    #pragma unroll
    for (int r = 0; r < 4; ++r) {
        cs0[r] = row16_reduce_add(cs0[r]);
        cs1[r] = row16_reduce_add(cs1[r]);
    }
    if (l15 == 15) {
        const int col = wave * 32 + quad * 4;
        if (LAYER == 2) {
            f32x4 o0, o1;
            #pragma unroll
            for (int r = 0; r < 4; ++r) { o0[r] = cs0[r] * (1.f / S_); o1[r] = cs1[r] * (1.f / S_); }
            *(f32x4*)(&out[set * H_ + col]) = o0;
            *(f32x4*)(&out[set * H_ + col + 16]) = o1;
        } else if (LAYER == 1) {
            *(f32x4*)(&g_colsum2[set * H_ + col]) = cs0;
            *(f32x4*)(&g_colsum2[set * H_ + col + 16]) = cs1;
        } else {
            *(f32x4*)(&g_colsum1[set * H_ + col]) = cs0;
            *(f32x4*)(&g_colsum1[set * H_ + col + 16]) = cs1;
        }
    }
}

extern "C" void kernel_launch(void* const* d_in, const int* in_sizes, int n_in,
                              void* d_out, int out_size, void* d_ws, size_t ws_size,
                              hipStream_t stream) {
    (void)in_sizes; (void)n_in; (void)out_size; (void)ws_size;
    const float* x  = (const float*)d_in[0];
    const float* W0 = (const float*)d_in[1];
    const float* b0 = (const float*)d_in[2];
    const float* W1 = (const float*)d_in[3];
    const float* b1 = (const float*)d_in[4];
    const float* W2 = (const float*)d_in[5];
    const float* b2 = (const float*)d_in[6];
    float* out = (float*)d_out;
    unsigned short* ws = (unsigned short*)d_ws;   // y: [256][1024][256] bf16 = 128 MiB

    prep_kernel<<<dim3(640), dim3(256), 0, stream>>>(W0, W1, W2);
    means0_kernel<<<dim3(256), dim3(1024), 0, stream>>>(x, b0);
    layer_kernel<0><<<dim3(256), dim3(512), 0, stream>>>(ws, out);
    c_kernel<1><<<dim3(64), dim3(256), 0, stream>>>(b1);
    layer_kernel<1><<<dim3(256), dim3(512), 0, stream>>>(ws, out);
    c_kernel<2><<<dim3(64), dim3(256), 0, stream>>>(b2);
    layer_kernel<2><<<dim3(256), dim3(512), 0, stream>>>(ws, out);
}

// Round 7
// 365.766 us; speedup vs baseline: 1.1276x; 1.0405x over previous
//
#include <hip/hip_runtime.h>

#define B_ 256
#define S_ 1024
#define D_ 128
#define H_ 256

typedef short short8 __attribute__((ext_vector_type(8)));
typedef float f32x4 __attribute__((ext_vector_type(4)));

// Cross-kernel buffers (re-written every call).
__device__ unsigned short g_Wb0[H_ * D_];   // bf16 left-halves, FRAG-ORDERED
__device__ unsigned short g_Wb1[H_ * H_];
__device__ unsigned short g_Wb2[H_ * H_];
__device__ float g_Wc0[H_ * D_];            // fp32: W_right + (W_left - bf16(W_left))
__device__ float g_Wc1[H_ * H_];
__device__ float g_Wc2[H_ * H_];
__device__ float g_c0[B_ * H_];             // per-set bias+mean vector for layer 0
__device__ unsigned short g_xb[(size_t)B_ * S_ * D_];  // bf16 x, row-swizzled (64 MiB)

__device__ __forceinline__ unsigned short f2bf(float x) {
    union { float f; unsigned u; } v; v.f = x;
    unsigned r = v.u + 0x7FFFu + ((v.u >> 16) & 1u);
    return (unsigned short)(r >> 16);
}
__device__ __forceinline__ float bf2f(unsigned short h) {
    union { float f; unsigned u; } v; v.u = ((unsigned)h) << 16;
    return v.f;
}
__device__ __forceinline__ float fast_tanh(float x) {
    float e = __builtin_amdgcn_exp2f(x * 2.885390081777927f); // 2*log2(e)
    float r = __builtin_amdgcn_rcpf(1.0f + e);
    return 1.0f - 2.0f * r;
}
__device__ __forceinline__ unsigned cvt_pk_bf16(float lo, float hi) {
    unsigned r;
    asm("v_cvt_pk_bf16_f32 %0, %1, %2" : "=v"(r) : "v"(lo), "v"(hi));
    return r;
}
__device__ __forceinline__ void gload_lds16(const unsigned short* g, unsigned short* l) {
    __builtin_amdgcn_global_load_lds(
        (const __attribute__((address_space(1))) void*)g,
        (__attribute__((address_space(3))) void*)l, 16, 0, 0);
}
template <int N>
__device__ __forceinline__ void vwait() {
    if constexpr (N == 0)       asm volatile("s_waitcnt vmcnt(0)" ::: "memory");
    else if constexpr (N == 4)  asm volatile("s_waitcnt vmcnt(4)" ::: "memory");
    else if constexpr (N == 8)  asm volatile("s_waitcnt vmcnt(8)" ::: "memory");
    else if constexpr (N == 10) asm volatile("s_waitcnt vmcnt(10)" ::: "memory");
    else if constexpr (N == 12) asm volatile("s_waitcnt vmcnt(12)" ::: "memory");
    else static_assert(N < 0, "unsupported vmcnt");
}
// Sum across each 16-lane group (DPP row_shr chain, pure VALU).
// Lane (l&15)==15 of each group ends up holding the 16-lane total.
__device__ __forceinline__ float row16_reduce_add(float v) {
    int s;
    s = __builtin_amdgcn_update_dpp(0, __builtin_bit_cast(int, v), 0x111, 0xF, 0xF, true);
    v += __builtin_bit_cast(float, s);
    s = __builtin_amdgcn_update_dpp(0, __builtin_bit_cast(int, v), 0x112, 0xF, 0xF, true);
    v += __builtin_bit_cast(float, s);
    s = __builtin_amdgcn_update_dpp(0, __builtin_bit_cast(int, v), 0x114, 0xF, 0xF, true);
    v += __builtin_bit_cast(float, s);
    s = __builtin_amdgcn_update_dpp(0, __builtin_bit_cast(int, v), 0x118, 0xF, 0xF, true);
    v += __builtin_bit_cast(float, s);
    return v;
}

// ---- prep: W left-halves -> bf16 frag-ordered; Wc fp32 correction ----------
__global__ __launch_bounds__(256) void prep_kernel(
    const float* __restrict__ W0, const float* __restrict__ W1,
    const float* __restrict__ W2)
{
    int i = blockIdx.x * 256 + threadIdx.x;
    const float* W; unsigned short* wb; float* wc; int kbits;
    if (i < H_ * D_) { W = W0; wb = g_Wb0; wc = g_Wc0; kbits = 7; }
    else {
        i -= H_ * D_;
        if (i < H_ * H_) { W = W1; wb = g_Wb1; wc = g_Wc1; kbits = 8; }
        else {
            i -= H_ * H_;
            if (i >= H_ * H_) return;
            W = W2; wb = g_Wb2; wc = g_Wc2; kbits = 8;
        }
    }
    const int K = 1 << kbits, KS = K >> 5;
    const int n = i >> kbits, k = i & (K - 1);
    const float a = W[n * 2 * K + k];
    const float b = W[n * 2 * K + K + k];
    const unsigned short hb = f2bf(a);
    // frag order: [w][cf][ks][lane][e] with lane = quad*16 + l15
    const int w = n >> 5, cf = (n >> 4) & 1, l15 = n & 15;
    const int ks = k >> 5, quad = (k >> 3) & 3, e = k & 7;
    wb[(((w * 2 + cf) * KS + ks) * 64 + quad * 16 + l15) * 8 + e] = hb;
    wc[n * K + k] = b + (a - bf2f(hb));
}

// ---- means0: col sums of x + bf16 swizzled copy + FUSED c0 computation -----
__global__ __launch_bounds__(1024) void means0_kernel(
    const float* __restrict__ x, const float* __restrict__ b0)
{
    const int set = blockIdx.x, t = threadIdx.x;
    const int cg = t & 31, rg = t >> 5;               // col-group of 4, row group
    const float* xs = x + (size_t)set * S_ * D_;
    unsigned short* xd = g_xb + (size_t)set * S_ * D_;
    const int slot = cg >> 1, halfsel = (cg & 1) * 4;
    f32x4 s = (f32x4){0.f, 0.f, 0.f, 0.f};
    #pragma unroll 8
    for (int i = 0; i < 32; ++i) {
        const int row = rg + i * 32;
        f32x4 v = *(const f32x4*)(xs + row * D_ + cg * 4);
        s += v;
        uint2 pv;
        pv.x = cvt_pk_bf16(v[0], v[1]);
        pv.y = cvt_pk_bf16(v[2], v[3]);
        *(uint2*)(&xd[row * D_ + ((slot ^ (row & 7)) * 8) + halfsel]) = pv;
    }
    __shared__ f32x4 red[32][32];
    __shared__ float m_lds[D_];
    red[rg][cg] = s;
    __syncthreads();
    if (t < 32) {
        f32x4 a = red[0][t];
        #pragma unroll
        for (int g = 1; g < 32; ++g) a += red[g][t];
        #pragma unroll
        for (int c = 0; c < 4; ++c) m_lds[t * 4 + c] = a[c] * (1.f / S_);
    }
    __syncthreads();
    // c0[set][j] = b0[j] + mean . Wc0[j]   (Wc0 is L2-resident, 128 KB)
    if (t < H_) {
        const float* wr = g_Wc0 + t * D_;
        float acc = 0.f;
        #pragma unroll 4
        for (int k = 0; k < D_; k += 4) {
            f32x4 w = *(const f32x4*)(wr + k);
            #pragma unroll
            for (int c = 0; c < 4; ++c) acc += m_lds[k + c] * w[c];
        }
        g_c0[set * H_ + t] = b0[t] + acc;
    }
}

// ---- fused 3-layer kernel helpers ------------------------------------------

template <int K>
__device__ __forceinline__ void stage_tile(
    const unsigned short* __restrict__ ysrc, unsigned short* lds, int tile, int tid)
{
    constexpr int NCH = (64 * K / 8) / 512;           // 16B chunks per thread
    const unsigned short* src = ysrc + tile * (64 * K);
    unsigned short* dst = lds + (tile % 3) * (64 * K);
    #pragma unroll
    for (int c = 0; c < NCH; ++c)
        gload_lds16(src + (c * 512 + tid) * 8, dst + (c * 512 + tid) * 8);
}

// One layer over 16 tiles of 64 rows, depth-2 pipeline (3 LDS buffers).
// Caller must have issued stage_tile(0) and stage_tile(1) already.
// Per iter: compute(t); SB0; stage(t+2); SB0; vmcnt(WN); s_barrier; SB0.
// At the wait, ops newer than stage(t+1) are exactly {stores(t), stage(t+2)}
// = WN, so vmcnt(WN) provably retires stage(t+1) while keeping one full tile
// of loads (+ stores) in flight across the barrier. Tails peeled (WT / none).
template <int K, bool STORES>
__device__ __forceinline__ void run_layer(
    const unsigned short* __restrict__ Wb,
    const unsigned short* __restrict__ ysrc,
    unsigned short* __restrict__ ydst,
    unsigned short* lds,
    const f32x4 creg0, const f32x4 creg1,
    f32x4& cs0, f32x4& cs1)
{
    constexpr int KS  = K / 32;
    constexpr int NCH = (64 * K / 8) / 512;
    constexpr int WN  = NCH + (STORES ? 8 : 0);
    constexpr int WT  = STORES ? 8 : 0;
    constexpr int NT  = S_ / 64;
    const int tid = threadIdx.x;
    const int lane = tid & 63, wave = tid >> 6;
    const int l15 = lane & 15, quad = lane >> 4;

    // W fragments: frag-ordered global layout -> perfectly coalesced b128 loads
    short8 wf[2][KS];
    {
        const unsigned short* wb = Wb + (wave * 2 * KS * 64 + lane) * 8;
        #pragma unroll
        for (int cf = 0; cf < 2; ++cf)
            #pragma unroll
            for (int ks = 0; ks < KS; ++ks)
                wf[cf][ks] = *(const short8*)(wb + (cf * KS + ks) * 512);
    }
    cs0 = (f32x4){0.f, 0.f, 0.f, 0.f};
    cs1 = (f32x4){0.f, 0.f, 0.f, 0.f};
    __syncthreads();   // stage(0),(1), wf retired everywhere; pipeline starts full

    for (int tt = 0; tt < NT; ++tt) {
        const unsigned short* yl = lds + (tt % 3) * (64 * K);
        #pragma unroll
        for (int rf = 0; rf < 4; ++rf) {
            short8 bfr[KS];
            #pragma unroll
            for (int ks = 0; ks < KS; ++ks)
                bfr[ks] = *(const short8*)(
                    &yl[(rf * 16 + l15) * K + (((ks * 4 + quad) ^ (l15 & 7)) * 8)]);
            f32x4 ac0 = (f32x4){0.f, 0.f, 0.f, 0.f};
            f32x4 ac1 = (f32x4){0.f, 0.f, 0.f, 0.f};
            #pragma unroll
            for (int ks = 0; ks < KS; ++ks) {
                ac0 = __builtin_amdgcn_mfma_f32_16x16x32_bf16(wf[0][ks], bfr[ks], ac0, 0, 0, 0);
                ac1 = __builtin_amdgcn_mfma_f32_16x16x32_bf16(wf[1][ks], bfr[ks], ac1, 0, 0, 0);
            }
            // D layout: lane -> y-row = tt*64+rf*16+l15 (B op),
            // cols = wave*32 + cf*16 + quad*4 + r (A op)
            const int row = tt * 64 + rf * 16 + l15;   // row&7 == l15&7
            f32x4 th0, th1;
            #pragma unroll
            for (int r = 0; r < 4; ++r) th0[r] = fast_tanh(ac0[r] + creg0[r]);
            #pragma unroll
            for (int r = 0; r < 4; ++r) th1[r] = fast_tanh(ac1[r] + creg1[r]);
            cs0 += th0; cs1 += th1;
            if (STORES) {
                const int slot0 = wave * 4 + (quad >> 1);     // cf=0
                const int slot1 = slot0 + 2;                  // cf=1
                uint2 p0, p1;
                p0.x = cvt_pk_bf16(th0[0], th0[1]); p0.y = cvt_pk_bf16(th0[2], th0[3]);
                p1.x = cvt_pk_bf16(th1[0], th1[1]); p1.y = cvt_pk_bf16(th1[2], th1[3]);
                unsigned short* yr = ydst + row * H_ + (quad & 1) * 4;
                *(uint2*)(&yr[(slot0 ^ (row & 7)) * 8]) = p0;
                *(uint2*)(&yr[(slot1 ^ (row & 7)) * 8]) = p1;
            }
        }
        __builtin_amdgcn_sched_barrier(0);       // pin: stores(t) before stage(t+2)
        if (tt + 2 < NT)
            stage_tile<K>(ysrc, lds, tt + 2, tid);
        __builtin_amdgcn_sched_barrier(0);       // pin: stage before wait
        if (tt < NT - 2)       vwait<WN>();
        else if (tt == NT - 2) vwait<WT>();
        __builtin_amdgcn_s_barrier();
        __builtin_amdgcn_sched_barrier(0);
    }
}

// c-phase: c[j] = bias[j] + (colsum/S) . Wc[j]; colsum_lds already populated.
__device__ __forceinline__ void c_phase(
    const float* __restrict__ Wc, const float* __restrict__ bias,
    const float* colsum_lds, float* cpart, float* c_lds)
{
    const int tid = threadIdx.x;
    const int j = tid >> 1, h = tid & 1;
    const float* wr = Wc + j * H_ + h * 128;
    float acc = 0.f;
    #pragma unroll 4
    for (int k = 0; k < 128; k += 4) {
        f32x4 w = *(const f32x4*)(wr + k);
        #pragma unroll
        for (int c = 0; c < 4; ++c)
            acc += colsum_lds[h * 128 + k + c] * w[c];
    }
    cpart[tid] = acc * (1.f / S_);
    __syncthreads();
    if (tid < H_) c_lds[tid] = bias[tid] + cpart[2 * tid] + cpart[2 * tid + 1];
    __syncthreads();
}

// ---- fused: L0 -> c1 -> L1 -> c2 -> L2, one block per set -----------------
// Mean dependency is block-local (block owns the whole set), so layers chain
// with __syncthreads only. y double-buffered in global (yA, yB) so no address
// is ever loaded-stored-reloaded by the same CU (L1 staleness impossible).
__global__ __launch_bounds__(512, 2) void fused_kernel(
    const float* __restrict__ b1, const float* __restrict__ b2,
    unsigned short* __restrict__ yA, unsigned short* __restrict__ yB,
    float* __restrict__ out)
{
    __shared__ __align__(16) unsigned short y_lds[3 * 64 * H_];   // 96 KB
    __shared__ float colsum_lds[H_];
    __shared__ float cpart[512];
    __shared__ float c_lds[H_];
    const int set = blockIdx.x;
    const int tid = threadIdx.x;
    const int lane = tid & 63, wave = tid >> 6;
    const int l15 = lane & 15, quad = lane >> 4;
    const int col = wave * 32 + quad * 4;

    const unsigned short* x0 = g_xb + (size_t)set * S_ * D_;
    unsigned short* ya = yA + (size_t)set * S_ * H_;
    unsigned short* yb = yB + (size_t)set * S_ * H_;
    f32x4 cs0, cs1, creg0, creg1;

    // ---------------- layer 0 (K=128, x -> yA) ----------------
    stage_tile<D_>(x0, y_lds, 0, tid);
    stage_tile<D_>(x0, y_lds, 1, tid);
    creg0 = *(const f32x4*)(g_c0 + set * H_ + col);
    creg1 = *(const f32x4*)(g_c0 + set * H_ + col + 16);
    run_layer<D_, true>(g_Wb0, x0, ya, y_lds, creg0, creg1, cs0, cs1);
    __syncthreads();                       // drain yA stores (everyone)

    #pragma unroll
    for (int r = 0; r < 4; ++r) { cs0[r] = row16_reduce_add(cs0[r]); cs1[r] = row16_reduce_add(cs1[r]); }
    if (l15 == 15) { *(f32x4*)&colsum_lds[col] = cs0; *(f32x4*)&colsum_lds[col + 16] = cs1; }
    // stage L1 tiles while c1 computes
    stage_tile<H_>(ya, y_lds, 0, tid);
    stage_tile<H_>(ya, y_lds, 1, tid);
    asm volatile("s_waitcnt lgkmcnt(0)" ::: "memory");   // colsum_lds visible,
    __builtin_amdgcn_s_barrier();                        // without draining vmcnt
    c_phase(g_Wc1, b1, colsum_lds, cpart, c_lds);
    creg0 = *(const f32x4*)&c_lds[col];
    creg1 = *(const f32x4*)&c_lds[col + 16];

    // ---------------- layer 1 (K=256, yA -> yB) ----------------
    run_layer<H_, true>(g_Wb1, ya, yb, y_lds, creg0, creg1, cs0, cs1);
    __syncthreads();                       // drain yB stores

    #pragma unroll
    for (int r = 0; r < 4; ++r) { cs0[r] = row16_reduce_add(cs0[r]); cs1[r] = row16_reduce_add(cs1[r]); }
    if (l15 == 15) { *(f32x4*)&colsum_lds[col] = cs0; *(f32x4*)&colsum_lds[col + 16] = cs1; }
    stage_tile<H_>(yb, y_lds, 0, tid);
    stage_tile<H_>(yb, y_lds, 1, tid);
    asm volatile("s_waitcnt lgkmcnt(0)" ::: "memory");
    __builtin_amdgcn_s_barrier();
    c_phase(g_Wc2, b2, colsum_lds, cpart, c_lds);
    creg0 = *(const f32x4*)&c_lds[col];
    creg1 = *(const f32x4*)&c_lds[col + 16];

    // ---------------- layer 2 (K=256, yB -> out) ----------------
    run_layer<H_, false>(g_Wb2, yb, yb, y_lds, creg0, creg1, cs0, cs1);

    #pragma unroll
    for (int r = 0; r < 4; ++r) { cs0[r] = row16_reduce_add(cs0[r]); cs1[r] = row16_reduce_add(cs1[r]); }
    if (l15 == 15) {
        f32x4 o0, o1;
        #pragma unroll
        for (int r = 0; r < 4; ++r) { o0[r] = cs0[r] * (1.f / S_); o1[r] = cs1[r] * (1.f / S_); }
        *(f32x4*)(&out[set * H_ + col]) = o0;
        *(f32x4*)(&out[set * H_ + col + 16]) = o1;
    }
}

extern "C" void kernel_launch(void* const* d_in, const int* in_sizes, int n_in,
                              void* d_out, int out_size, void* d_ws, size_t ws_size,
                              hipStream_t stream) {
    (void)in_sizes; (void)n_in; (void)out_size; (void)ws_size;
    const float* x  = (const float*)d_in[0];
    const float* W0 = (const float*)d_in[1];
    const float* b0 = (const float*)d_in[2];
    const float* W1 = (const float*)d_in[3];
    const float* b1 = (const float*)d_in[4];
    const float* W2 = (const float*)d_in[5];
    const float* b2 = (const float*)d_in[6];
    float* out = (float*)d_out;
    unsigned short* yA = (unsigned short*)d_ws;                          // 128 MiB
    unsigned short* yB = yA + (size_t)B_ * S_ * H_;                      // 128 MiB

    prep_kernel<<<dim3(640), dim3(256), 0, stream>>>(W0, W1, W2);
    means0_kernel<<<dim3(256), dim3(1024), 0, stream>>>(x, b0);
    fused_kernel<<<dim3(256), dim3(512), 0, stream>>>(b1, b2, yA, yB, out);
}